// Round 1
// baseline (151.846 us; speedup 1.0000x reference)
//
#include <hip/hip_runtime.h>
#include <hip/hip_bf16.h>

// NT-Xent loss: z1,z2 [4096,256] fp32 -> scalar loss.
// loss = mean_i [ log(sum_{j!=i} exp(dot(zn_i,zn_j)*2)) - dot(zn_i, zn_pair(i))*2 ]
// Strategy: normalize in fp32, quantize to bf16, MFMA self-GEMM with fused
// exp+rowsum epilogue (no max subtraction needed: sim in [-2,2]),
// subtract exp(diag) afterwards; positive-pair term in pure fp32.

#define TWO_N 8192
#define NPAIR 4096
#define DDIM  256
#define INV_T 2.0f

typedef __attribute__((ext_vector_type(8))) short bf16x8;
typedef __attribute__((ext_vector_type(4))) float f32x4;

// ---------------- Kernel 1: normalize + quantize ----------------
// grid 2048 x 256: one wave per row.
__global__ void k_normalize(const float* __restrict__ z1,
                            const float* __restrict__ z2,
                            __hip_bfloat16* __restrict__ zn,
                            float* __restrict__ e_diag,
                            float* __restrict__ inv_norm) {
    const int w    = threadIdx.x >> 6;
    const int lane = threadIdx.x & 63;
    const int r    = blockIdx.x * 4 + w;

    const float* src = (r < NPAIR) ? (z1 + (size_t)r * DDIM)
                                   : (z2 + (size_t)(r - NPAIR) * DDIM);
    float4 v = ((const float4*)src)[lane];

    float ss = v.x * v.x + v.y * v.y + v.z * v.z + v.w * v.w;
#pragma unroll
    for (int m = 1; m < 64; m <<= 1) ss += __shfl_xor(ss, m, 64);

    float norm = fmaxf(sqrtf(ss), 1e-8f);   // matches reference eps
    float inv  = 1.0f / norm;

    __hip_bfloat16 q[4];
    q[0] = __float2bfloat16(v.x * inv);
    q[1] = __float2bfloat16(v.y * inv);
    q[2] = __float2bfloat16(v.z * inv);
    q[3] = __float2bfloat16(v.w * inv);

    float qss = 0.0f;
#pragma unroll
    for (int j = 0; j < 4; ++j) {
        float qf = __bfloat162float(q[j]);
        qss += qf * qf;
    }
#pragma unroll
    for (int m = 1; m < 64; m <<= 1) qss += __shfl_xor(qss, m, 64);

    // 8B vectorized store of 4 bf16
    *reinterpret_cast<uint2*>(zn + (size_t)r * DDIM + lane * 4) =
        *reinterpret_cast<uint2*>(q);

    if (lane == 0) {
        e_diag[r]   = __expf(qss * INV_T);  // same bf16 self-dot the GEMM computes
        inv_norm[r] = inv;
    }
}

// ---------------- Kernel 2: MFMA self-GEMM + exp + rowsum ----------------
// grid = 64 row-tiles x 16 col-slices = 1024 blocks, 256 threads (4 waves).
// Each block: rows [rt*128,+128), cols [sl*512,+512) as 4 col-tiles of 128.
// LDS-staged 128x64 bf16 chunks (padded +8 to break bank aliasing).
#define BK 64
#define LDP (BK + 8)   // 72 bf16 row stride -> 144B -> rows r,r+8 alias (2-way, free)

__global__ __launch_bounds__(256)
void k_gemm_sumexp(const __hip_bfloat16* __restrict__ zn,
                   float* __restrict__ row_sumexp) {
    __shared__ __hip_bfloat16 Asmem[128][LDP];
    __shared__ __hip_bfloat16 Bsmem[128][LDP];

    const int tid  = threadIdx.x;
    const int lane = tid & 63;
    const int w    = tid >> 6;
    const int wr   = w >> 1;       // wave row-half
    const int wc   = w & 1;        // wave col-half
    const int lr   = lane & 15;
    const int quad = lane >> 4;

    const int rt = blockIdx.x >> 4;       // 0..63
    const int sl = blockIdx.x & 15;       // 0..15
    const int row_base = rt * 128;

    float rs[4][4];                       // per-lane row-sum accum (rows fixed per lane)
#pragma unroll
    for (int mi = 0; mi < 4; ++mi)
#pragma unroll
        for (int r = 0; r < 4; ++r) rs[mi][r] = 0.0f;

    for (int ct = 0; ct < 4; ++ct) {
        const int col_base = sl * 512 + ct * 128;

        f32x4 acc[4][4];
#pragma unroll
        for (int mi = 0; mi < 4; ++mi)
#pragma unroll
            for (int ni = 0; ni < 4; ++ni) acc[mi][ni] = (f32x4){0.f, 0.f, 0.f, 0.f};

        for (int kk = 0; kk < DDIM; kk += BK) {
            __syncthreads();   // protect LDS from previous iteration's readers
            // stage A chunk: 128 rows x 64 bf16 = 1024 16B-chunks, 4 per thread
#pragma unroll
            for (int i = 0; i < 4; ++i) {
                int c   = tid + i * 256;
                int row = c >> 3;
                int o   = c & 7;
                uint4 va = *reinterpret_cast<const uint4*>(
                    zn + (size_t)(row_base + row) * DDIM + kk + o * 8);
                *reinterpret_cast<uint4*>(&Asmem[row][o * 8]) = va;
                uint4 vb = *reinterpret_cast<const uint4*>(
                    zn + (size_t)(col_base + row) * DDIM + kk + o * 8);
                *reinterpret_cast<uint4*>(&Bsmem[row][o * 8]) = vb;
            }
            __syncthreads();

#pragma unroll
            for (int ks = 0; ks < BK; ks += 32) {
                bf16x8 af[4], bf[4];
#pragma unroll
                for (int mi = 0; mi < 4; ++mi)
                    af[mi] = *reinterpret_cast<const bf16x8*>(
                        &Asmem[wr * 64 + mi * 16 + lr][ks + quad * 8]);
#pragma unroll
                for (int ni = 0; ni < 4; ++ni)
                    bf[ni] = *reinterpret_cast<const bf16x8*>(
                        &Bsmem[wc * 64 + ni * 16 + lr][ks + quad * 8]);
#pragma unroll
                for (int mi = 0; mi < 4; ++mi)
#pragma unroll
                    for (int ni = 0; ni < 4; ++ni)
                        acc[mi][ni] = __builtin_amdgcn_mfma_f32_16x16x32_bf16(
                            af[mi], bf[ni], acc[mi][ni], 0, 0, 0);
            }
        }

        // epilogue for this col-tile: exp(2*dot), accumulate per-lane row sums.
        // C/D layout (m89-verified): col = lane&15, row = quad*4 + reg.
#pragma unroll
        for (int mi = 0; mi < 4; ++mi)
#pragma unroll
            for (int ni = 0; ni < 4; ++ni)
#pragma unroll
                for (int r = 0; r < 4; ++r)
                    rs[mi][r] += __expf(acc[mi][ni][r] * INV_T);
    }

    // reduce rs over the 16 column-lanes (bits 0..3 of lane), then atomicAdd.
#pragma unroll
    for (int mi = 0; mi < 4; ++mi) {
#pragma unroll
        for (int r = 0; r < 4; ++r) {
            float v = rs[mi][r];
            v += __shfl_xor(v, 1, 64);
            v += __shfl_xor(v, 2, 64);
            v += __shfl_xor(v, 4, 64);
            v += __shfl_xor(v, 8, 64);
            if (lr == 0) {
                int row = row_base + wr * 64 + mi * 16 + quad * 4 + r;
                atomicAdd(&row_sumexp[row], v);
            }
        }
    }
}

// ---------------- Kernel 3: positive pairs + final loss ----------------
// grid 1024 x 256: one wave per pair (fp32 dot, matches reference precision).
__global__ void k_loss(const float* __restrict__ z1,
                       const float* __restrict__ z2,
                       const float* __restrict__ row_sumexp,
                       const float* __restrict__ e_diag,
                       const float* __restrict__ inv_norm,
                       float* __restrict__ out) {
    const int w    = threadIdx.x >> 6;
    const int lane = threadIdx.x & 63;
    const int i    = blockIdx.x * 4 + w;

    float4 a = ((const float4*)(z1 + (size_t)i * DDIM))[lane];
    float4 b = ((const float4*)(z2 + (size_t)i * DDIM))[lane];
    float d = a.x * b.x + a.y * b.y + a.z * b.z + a.w * b.w;
#pragma unroll
    for (int m = 1; m < 64; m <<= 1) d += __shfl_xor(d, m, 64);

    __shared__ float p[4];
    if (lane == 0) {
        float pos = d * inv_norm[i] * inv_norm[i + NPAIR] * INV_T;
        float Slo = row_sumexp[i] - e_diag[i];
        float Shi = row_sumexp[i + NPAIR] - e_diag[i + NPAIR];
        p[w] = (logf(Slo) - pos) + (logf(Shi) - pos);
    }
    __syncthreads();
    if (threadIdx.x == 0) {
        float t = (p[0] + p[1] + p[2] + p[3]) * (1.0f / (float)TWO_N);
        atomicAdd(out, t);
    }
}

extern "C" void kernel_launch(void* const* d_in, const int* in_sizes, int n_in,
                              void* d_out, int out_size, void* d_ws, size_t ws_size,
                              hipStream_t stream) {
    const float* z1 = (const float*)d_in[0];
    const float* z2 = (const float*)d_in[1];
    float* out = (float*)d_out;

    char* ws = (char*)d_ws;
    __hip_bfloat16* zn  = (__hip_bfloat16*)ws;                       // 4 MB
    float* row_sumexp   = (float*)(ws + (size_t)TWO_N * DDIM * 2);   // 32 KB
    float* e_diag       = row_sumexp + TWO_N;                        // 32 KB
    float* inv_norm     = e_diag + TWO_N;                            // 32 KB

    hipMemsetAsync(out, 0, sizeof(float), stream);
    hipMemsetAsync(row_sumexp, 0, TWO_N * sizeof(float), stream);

    k_normalize<<<TWO_N / 4, 256, 0, stream>>>(z1, z2, zn, e_diag, inv_norm);
    k_gemm_sumexp<<<1024, 256, 0, stream>>>(zn, row_sumexp);
    k_loss<<<NPAIR / 4, 256, 0, stream>>>(z1, z2, row_sumexp, e_diag, inv_norm, out);
}

// Round 2
// 131.115 us; speedup vs baseline: 1.1581x; 1.1581x over previous
//
#include <hip/hip_runtime.h>
#include <hip/hip_bf16.h>

// NT-Xent loss: z1,z2 [4096,256] fp32 -> scalar loss.
// R2: exploit sim symmetry (upper-triangle 128x128 tiles only, scatter row+col
// exp-sums) + global_load_lds(16B) staging with XOR-swizzled LDS layout
// (swizzle applied via the global-address permutation, so the wave-uniform
// base + lane*16 constraint is satisfied AND fragment ds_read_b128 are at the
// 8-dword/bank minimum).

#define TWO_N 8192
#define NPAIR 4096
#define DDIM  256
#define NT    64                    // 128-row tiles per dim
#define NBLK  (NT * (NT + 1) / 2)   // 2080 upper-triangle tiles
#define INV_T 2.0f

typedef __attribute__((ext_vector_type(8))) short bf16x8;
typedef __attribute__((ext_vector_type(4))) float f32x4;

typedef __attribute__((address_space(1))) void gvoid_t;
typedef __attribute__((address_space(3))) void lvoid_t;

__device__ __forceinline__ void gload_lds16(const void* g, void* l) {
    __builtin_amdgcn_global_load_lds((gvoid_t*)g, (lvoid_t*)l, 16, 0, 0);
}

// ---------------- Kernel 1: normalize + quantize + zero scratch ----------------
// grid 2048 x 256: one wave per row; each block also zeros 4 row_sumexp entries.
__global__ void k_normalize(const float* __restrict__ z1,
                            const float* __restrict__ z2,
                            __hip_bfloat16* __restrict__ zn,
                            float* __restrict__ e_diag,
                            float* __restrict__ inv_norm,
                            float* __restrict__ row_sumexp,
                            float* __restrict__ out) {
    if (threadIdx.x < 4) row_sumexp[blockIdx.x * 4 + threadIdx.x] = 0.0f;
    if (blockIdx.x == 0 && threadIdx.x == 0) out[0] = 0.0f;

    const int w    = threadIdx.x >> 6;
    const int lane = threadIdx.x & 63;
    const int r    = blockIdx.x * 4 + w;

    const float* src = (r < NPAIR) ? (z1 + (size_t)r * DDIM)
                                   : (z2 + (size_t)(r - NPAIR) * DDIM);
    float4 v = ((const float4*)src)[lane];

    float ss = v.x * v.x + v.y * v.y + v.z * v.z + v.w * v.w;
#pragma unroll
    for (int m = 1; m < 64; m <<= 1) ss += __shfl_xor(ss, m, 64);

    float norm = fmaxf(sqrtf(ss), 1e-8f);   // matches reference eps
    float inv  = 1.0f / norm;

    __hip_bfloat16 q[4];
    q[0] = __float2bfloat16(v.x * inv);
    q[1] = __float2bfloat16(v.y * inv);
    q[2] = __float2bfloat16(v.z * inv);
    q[3] = __float2bfloat16(v.w * inv);

    float qss = 0.0f;
#pragma unroll
    for (int j = 0; j < 4; ++j) {
        float qf = __bfloat162float(q[j]);
        qss += qf * qf;
    }
#pragma unroll
    for (int m = 1; m < 64; m <<= 1) qss += __shfl_xor(qss, m, 64);

    *reinterpret_cast<uint2*>(zn + (size_t)r * DDIM + lane * 4) =
        *reinterpret_cast<uint2*>(q);

    if (lane == 0) {
        e_diag[r]   = __expf(qss * INV_T);  // same bf16 self-dot the GEMM computes
        inv_norm[r] = inv;
    }
}

// ---------------- Kernel 2: symmetric MFMA self-GEMM + exp + row/col sums ----
// 2080 blocks (upper-triangle 128x128 tiles), 256 threads (2x2 waves of 64x64).
// LDS: unswizzled-linear slots; slot s holds (row=s>>3, chunk=(s&7)^(row&7)),
// 16B chunks of BK=64 bf16 K-panel. Staged via global_load_lds (16B/lane).
__global__ __launch_bounds__(256)
void k_gemm_sumexp(const __hip_bfloat16* __restrict__ zn,
                   float* __restrict__ row_sumexp) {
    __shared__ __hip_bfloat16 Asmem[128 * 64];   // 16 KB
    __shared__ __hip_bfloat16 Bsmem[128 * 64];   // 16 KB

    const int tid  = threadIdx.x;
    const int lane = tid & 63;
    const int w    = tid >> 6;
    const int wr   = w >> 1;          // wave row-half (0/1)
    const int wc   = w & 1;           // wave col-half (0/1)
    const int lr   = lane & 15;
    const int quad = lane >> 4;

    // --- triangular decode: block b -> (rt, ct), rt <= ct ---
    int b  = blockIdx.x;
    int rt = (int)(64.5f - sqrtf(64.5f * 64.5f - 2.0f * (float)b));
    if (rt < 0) rt = 0;
    if (rt > NT - 1) rt = NT - 1;
    while (rt > 0 && NT * rt - (rt * (rt - 1)) / 2 > b) --rt;
    while (NT * (rt + 1) - ((rt + 1) * rt) / 2 <= b) ++rt;
    const int ct   = rt + (b - (NT * rt - (rt * (rt - 1)) / 2));
    const bool diag = (rt == ct);

    const int row_base = rt * 128;
    const int col_base = ct * 128;

    // --- staging addresses (lane-invariant swizzle) ---
    // slot s = i*256 + w*64 + lane; row = s>>3 = i*32 + w*8 + (lane>>3);
    // chunk = (s&7)^(row&7) = (lane&7)^(lane>>3)  [w*8, i*32 vanish mod 8]
    const int srow   = lane >> 3;
    const int schunk = (lane & 7) ^ srow;
    const size_t g_lane_off = (size_t)(w * 8 + srow) * (DDIM * 2) + (size_t)schunk * 16;

    const char* gA = (const char*)(zn + (size_t)row_base * DDIM) + g_lane_off;
    const char* gB = (const char*)(zn + (size_t)col_base * DDIM) + g_lane_off;
    __hip_bfloat16* lA = Asmem + (size_t)(w * 64 + lane) * 8;
    __hip_bfloat16* lB = Bsmem + (size_t)(w * 64 + lane) * 8;

    // --- fragment read base pointers (swizzled) ---
    // A frag mi: row = wr*64 + mi*16 + lr, chunk = ksc + quad (ksc in {0,4})
    // slot = row*8 + ((ksc+quad) ^ (lr&7));  ksc=4 flips byte-addr bit 6.
    const int sw = quad ^ (lane & 7);
    const char* a0lo = (const char*)Asmem + ((size_t)(wr * 64 + lr) * 8 + sw) * 16;
    const char* b0lo = (const char*)Bsmem + ((size_t)(wc * 64 + lr) * 8 + sw) * 16;
    const char* a0hi = (const char*)((uintptr_t)a0lo ^ 64);
    const char* b0hi = (const char*)((uintptr_t)b0lo ^ 64);

    f32x4 acc[4][4];
#pragma unroll
    for (int mi = 0; mi < 4; ++mi)
#pragma unroll
        for (int ni = 0; ni < 4; ++ni) acc[mi][ni] = (f32x4){0.f, 0.f, 0.f, 0.f};

#pragma unroll
    for (int kk = 0; kk < 4; ++kk) {           // K panels of 64 bf16
        __syncthreads();                       // protect LDS from prev readers
#pragma unroll
        for (int i = 0; i < 4; ++i) {
            gload_lds16(gA + (size_t)i * 32 * (DDIM * 2) + kk * 128, lA + (size_t)i * 256 * 8);
            gload_lds16(gB + (size_t)i * 32 * (DDIM * 2) + kk * 128, lB + (size_t)i * 256 * 8);
        }
        __syncthreads();                       // drains vmcnt (global_load_lds)

#pragma unroll
        for (int ks2 = 0; ks2 < 2; ++ks2) {
            const char* aSel = ks2 ? a0hi : a0lo;
            const char* bSel = ks2 ? b0hi : b0lo;
            bf16x8 af[4], bfr[4];
#pragma unroll
            for (int mi = 0; mi < 4; ++mi)
                af[mi] = *reinterpret_cast<const bf16x8*>(aSel + mi * 2048);
#pragma unroll
            for (int ni = 0; ni < 4; ++ni)
                bfr[ni] = *reinterpret_cast<const bf16x8*>(bSel + ni * 2048);
#pragma unroll
            for (int mi = 0; mi < 4; ++mi)
#pragma unroll
                for (int ni = 0; ni < 4; ++ni)
                    acc[mi][ni] = __builtin_amdgcn_mfma_f32_16x16x32_bf16(
                        af[mi], bfr[ni], acc[mi][ni], 0, 0, 0);
        }
    }

    // --- epilogue: e = exp(2*dot); row-sums always, col-sums if off-diag ---
    // C/D layout (verified R1): col = lane&15, row = quad*4 + reg.
    float rs[4][4];
    float cs[4];
#pragma unroll
    for (int mi = 0; mi < 4; ++mi)
#pragma unroll
        for (int r = 0; r < 4; ++r) rs[mi][r] = 0.0f;
#pragma unroll
    for (int ni = 0; ni < 4; ++ni) cs[ni] = 0.0f;

#pragma unroll
    for (int mi = 0; mi < 4; ++mi)
#pragma unroll
        for (int ni = 0; ni < 4; ++ni)
#pragma unroll
            for (int r = 0; r < 4; ++r) {
                float e = __expf(acc[mi][ni][r] * INV_T);
                rs[mi][r] += e;
                cs[ni] += e;
            }

    // row sums: reduce over lane bits 0..3 (the 16 columns)
#pragma unroll
    for (int mi = 0; mi < 4; ++mi) {
#pragma unroll
        for (int r = 0; r < 4; ++r) {
            float v = rs[mi][r];
            v += __shfl_xor(v, 1, 64);
            v += __shfl_xor(v, 2, 64);
            v += __shfl_xor(v, 4, 64);
            v += __shfl_xor(v, 8, 64);
            if (lr == 0) {
                int row = row_base + wr * 64 + mi * 16 + quad * 4 + r;
                atomicAdd(&row_sumexp[row], v);
            }
        }
    }

    // col sums: reduce over lane bits 4..5 (the 16 rows per reg already folded)
    if (!diag) {
#pragma unroll
        for (int ni = 0; ni < 4; ++ni) {
            float v = cs[ni];
            v += __shfl_xor(v, 16, 64);
            v += __shfl_xor(v, 32, 64);
            if (quad == 0) {
                int col = col_base + wc * 64 + ni * 16 + lr;
                atomicAdd(&row_sumexp[col], v);
            }
        }
    }
}

// ---------------- Kernel 3: positive pairs + final loss ----------------
__global__ void k_loss(const float* __restrict__ z1,
                       const float* __restrict__ z2,
                       const float* __restrict__ row_sumexp,
                       const float* __restrict__ e_diag,
                       const float* __restrict__ inv_norm,
                       float* __restrict__ out) {
    const int w    = threadIdx.x >> 6;
    const int lane = threadIdx.x & 63;
    const int i    = blockIdx.x * 4 + w;

    float4 a = ((const float4*)(z1 + (size_t)i * DDIM))[lane];
    float4 b = ((const float4*)(z2 + (size_t)i * DDIM))[lane];
    float d = a.x * b.x + a.y * b.y + a.z * b.z + a.w * b.w;
#pragma unroll
    for (int m = 1; m < 64; m <<= 1) d += __shfl_xor(d, m, 64);

    __shared__ float p[4];
    if (lane == 0) {
        float pos = d * inv_norm[i] * inv_norm[i + NPAIR] * INV_T;
        float Slo = row_sumexp[i] - e_diag[i];
        float Shi = row_sumexp[i + NPAIR] - e_diag[i + NPAIR];
        p[w] = (logf(Slo) - pos) + (logf(Shi) - pos);
    }
    __syncthreads();
    if (threadIdx.x == 0) {
        float t = (p[0] + p[1] + p[2] + p[3]) * (1.0f / (float)TWO_N);
        atomicAdd(out, t);
    }
}

extern "C" void kernel_launch(void* const* d_in, const int* in_sizes, int n_in,
                              void* d_out, int out_size, void* d_ws, size_t ws_size,
                              hipStream_t stream) {
    const float* z1 = (const float*)d_in[0];
    const float* z2 = (const float*)d_in[1];
    float* out = (float*)d_out;

    char* ws = (char*)d_ws;
    __hip_bfloat16* zn  = (__hip_bfloat16*)ws;                       // 4 MB
    float* row_sumexp   = (float*)(ws + (size_t)TWO_N * DDIM * 2);   // 32 KB
    float* e_diag       = row_sumexp + TWO_N;                        // 32 KB
    float* inv_norm     = e_diag + TWO_N;                            // 32 KB

    k_normalize<<<TWO_N / 4, 256, 0, stream>>>(z1, z2, zn, e_diag, inv_norm,
                                               row_sumexp, out);
    k_gemm_sumexp<<<NBLK, 256, 0, stream>>>(zn, row_sumexp);
    k_loss<<<NPAIR / 4, 256, 0, stream>>>(z1, z2, row_sumexp, e_diag, inv_norm, out);
}

// Round 3
// 126.312 us; speedup vs baseline: 1.2022x; 1.0380x over previous
//
#include <hip/hip_runtime.h>
#include <hip/hip_bf16.h>

// NT-Xent loss: z1,z2 [4096,256] fp32 -> scalar loss.
// R3: GEMM restructured to remove the per-panel barrier drains that killed R2:
//  - full-K A-tile (128x256 bf16 = 64KB) staged once via global_load_lds,
//    XOR-swizzled, ONE __syncthreads per block;
//  - B fragments streamed directly from global (L2-hot), no barriers in the
//    MFMA loop, explicit next-kstep register prefetch;
//  - 64KB LDS -> 2 blocks/CU so A-staging of one block overlaps compute of the
//    other. Triangle symmetry + fused exp/row/col sums kept from R2.
// Also: pair-dot folded into k_normalize; k_loss reduced to a tiny finisher.

#define TWO_N 8192
#define NPAIR 4096
#define DDIM  256
#define NT    64                    // 128-row tiles per dim
#define NBLK  (NT * (NT + 1) / 2)   // 2080 upper-triangle tiles
#define INV_T 2.0f

typedef __attribute__((ext_vector_type(8))) short bf16x8;
typedef __attribute__((ext_vector_type(4))) float f32x4;

typedef __attribute__((address_space(1))) void gvoid_t;
typedef __attribute__((address_space(3))) void lvoid_t;

__device__ __forceinline__ void gload_lds16(const void* g, void* l) {
    __builtin_amdgcn_global_load_lds((gvoid_t*)g, (lvoid_t*)l, 16, 0, 0);
}

// ---------------- Kernel 1: normalize + quantize + pair-dot + zero scratch --
// grid 1024 x 256: one wave per PAIR i (handles rows i and i+4096).
__global__ void k_normalize(const float* __restrict__ z1,
                            const float* __restrict__ z2,
                            __hip_bfloat16* __restrict__ zn,
                            float* __restrict__ e_diag,
                            float* __restrict__ pos,
                            float* __restrict__ row_sumexp,
                            float* __restrict__ out) {
    if (threadIdx.x < 8) row_sumexp[blockIdx.x * 8 + threadIdx.x] = 0.0f;
    if (blockIdx.x == 0 && threadIdx.x == 0) out[0] = 0.0f;

    const int w    = threadIdx.x >> 6;
    const int lane = threadIdx.x & 63;
    const int i    = blockIdx.x * 4 + w;

    float4 a = ((const float4*)(z1 + (size_t)i * DDIM))[lane];
    float4 b = ((const float4*)(z2 + (size_t)i * DDIM))[lane];

    float s1 = a.x * a.x + a.y * a.y + a.z * a.z + a.w * a.w;
    float s2 = b.x * b.x + b.y * b.y + b.z * b.z + b.w * b.w;
    float dd = a.x * b.x + a.y * b.y + a.z * b.z + a.w * b.w;
#pragma unroll
    for (int m = 1; m < 64; m <<= 1) {
        s1 += __shfl_xor(s1, m, 64);
        s2 += __shfl_xor(s2, m, 64);
        dd += __shfl_xor(dd, m, 64);
    }

    float inv1 = 1.0f / fmaxf(sqrtf(s1), 1e-8f);   // matches reference eps
    float inv2 = 1.0f / fmaxf(sqrtf(s2), 1e-8f);

    __hip_bfloat16 q1[4], q2[4];
    q1[0] = __float2bfloat16(a.x * inv1); q1[1] = __float2bfloat16(a.y * inv1);
    q1[2] = __float2bfloat16(a.z * inv1); q1[3] = __float2bfloat16(a.w * inv1);
    q2[0] = __float2bfloat16(b.x * inv2); q2[1] = __float2bfloat16(b.y * inv2);
    q2[2] = __float2bfloat16(b.z * inv2); q2[3] = __float2bfloat16(b.w * inv2);

    float qs1 = 0.0f, qs2 = 0.0f;
#pragma unroll
    for (int j = 0; j < 4; ++j) {
        float f1 = __bfloat162float(q1[j]);
        float f2 = __bfloat162float(q2[j]);
        qs1 += f1 * f1;
        qs2 += f2 * f2;
    }
#pragma unroll
    for (int m = 1; m < 64; m <<= 1) {
        qs1 += __shfl_xor(qs1, m, 64);
        qs2 += __shfl_xor(qs2, m, 64);
    }

    *reinterpret_cast<uint2*>(zn + (size_t)i * DDIM + lane * 4) =
        *reinterpret_cast<uint2*>(q1);
    *reinterpret_cast<uint2*>(zn + (size_t)(i + NPAIR) * DDIM + lane * 4) =
        *reinterpret_cast<uint2*>(q2);

    if (lane == 0) {
        e_diag[i]         = __expf(qs1 * INV_T);   // matches GEMM's bf16 self-dot
        e_diag[i + NPAIR] = __expf(qs2 * INV_T);
        pos[i]            = dd * inv1 * inv2 * INV_T;  // positive-pair term, pure fp32
    }
}

// ---------------- Kernel 2: symmetric MFMA self-GEMM + exp + row/col sums ----
// 2080 blocks (upper-triangle 128x128 tiles), 256 threads (2x2 waves of 64x64).
// A-tile full K in LDS (swizzled: row r, 16B-chunk slot c' holds global chunk
// ck with ck = (c'&24) | ((c'&7)^(r&7))), staged with global_load_lds(16B).
// B fragments read directly from global per kstep (16 full 64B lines / instr).
__global__ __launch_bounds__(256)
void k_gemm_sumexp(const __hip_bfloat16* __restrict__ zn,
                   float* __restrict__ row_sumexp) {
    __shared__ __align__(128) __hip_bfloat16 Asmem[128 * DDIM];   // 64 KB

    const int tid  = threadIdx.x;
    const int lane = tid & 63;
    const int w    = tid >> 6;
    const int wr   = w >> 1;          // wave row-half (0/1)
    const int wc   = w & 1;           // wave col-half (0/1)
    const int lr   = lane & 15;
    const int quad = lane >> 4;

    // --- triangular decode: block b -> (rt, ct), rt <= ct (verified R2) ---
    int b  = blockIdx.x;
    int rt = (int)(64.5f - sqrtf(64.5f * 64.5f - 2.0f * (float)b));
    if (rt < 0) rt = 0;
    if (rt > NT - 1) rt = NT - 1;
    while (rt > 0 && NT * rt - (rt * (rt - 1)) / 2 > b) --rt;
    while (NT * (rt + 1) - ((rt + 1) * rt) / 2 <= b) ++rt;
    const int ct   = rt + (b - (NT * rt - (rt * (rt - 1)) / 2));
    const bool diag = (rt == ct);

    const int row_base = rt * 128;
    const int col_base = ct * 128;

    // --- stage A tile: slot s = j*256+tid -> row = j*8 + (tid>>5), c' = tid&31;
    //     source chunk ck is per-thread constant. 16 rounds of 16B/lane. ---
    {
        const int ck = (tid & 24) | ((tid & 7) ^ (tid >> 5));
        const char* gA = (const char*)(zn + (size_t)row_base * DDIM)
                       + (tid >> 5) * (DDIM * 2) + ck * 16;
        char* lA = (char*)Asmem + tid * 16;
#pragma unroll
        for (int j = 0; j < 16; ++j)
            gload_lds16(gA + (size_t)j * 8 * (DDIM * 2), lA + j * 4096);
    }
    __syncthreads();   // the ONLY barrier (drains the A staging)

    // --- A fragment LDS byte offsets (swizzled) ---
    // A(mi,kstep): row = wr*64+mi*16+lr, byte = row*512 + (kstep>>1)*128
    //              + [ (quad ^ (lr&7)) ^ ((kstep&1)<<2) ] * 16
    int pa[4];
#pragma unroll
    for (int mi = 0; mi < 4; ++mi)
        pa[mi] = (wr * 64 + mi * 16 + lr) * (DDIM * 2) + ((quad ^ (lr & 7)) << 4);

    // --- B fragment global pointers: row = col_base + wc*64 + ni*16 + lr ---
    const __hip_bfloat16* gB[4];
#pragma unroll
    for (int ni = 0; ni < 4; ++ni)
        gB[ni] = zn + (size_t)(col_base + wc * 64 + ni * 16 + lr) * DDIM + quad * 8;

    f32x4 acc[4][4];
#pragma unroll
    for (int mi = 0; mi < 4; ++mi)
#pragma unroll
        for (int ni = 0; ni < 4; ++ni) acc[mi][ni] = (f32x4){0.f, 0.f, 0.f, 0.f};

    bf16x8 afc[4], bfc[4];
#pragma unroll
    for (int ni = 0; ni < 4; ++ni) bfc[ni] = *(const bf16x8*)(gB[ni]);
#pragma unroll
    for (int mi = 0; mi < 4; ++mi)
        afc[mi] = *(const bf16x8*)((const char*)Asmem + pa[mi]);

#pragma unroll
    for (int kstep = 0; kstep < 8; ++kstep) {
        bf16x8 afn[4], bfn[4];
        if (kstep < 7) {
            const int kn   = kstep + 1;
            const int koff = ((kn >> 1) << 7);
            const int kx   = ((kn & 1) << 6);
#pragma unroll
            for (int ni = 0; ni < 4; ++ni)
                bfn[ni] = *(const bf16x8*)(gB[ni] + kn * 32);
#pragma unroll
            for (int mi = 0; mi < 4; ++mi)
                afn[mi] = *(const bf16x8*)((const char*)Asmem + ((pa[mi] ^ kx) + koff));
        }
#pragma unroll
        for (int mi = 0; mi < 4; ++mi)
#pragma unroll
            for (int ni = 0; ni < 4; ++ni)
                acc[mi][ni] = __builtin_amdgcn_mfma_f32_16x16x32_bf16(
                    afc[mi], bfc[ni], acc[mi][ni], 0, 0, 0);
        if (kstep < 7) {
#pragma unroll
            for (int mi = 0; mi < 4; ++mi) afc[mi] = afn[mi];
#pragma unroll
            for (int ni = 0; ni < 4; ++ni) bfc[ni] = bfn[ni];
        }
    }

    // --- epilogue: e = exp(2*dot); row-sums always, col-sums if off-diag ---
    // C/D layout (verified R1/R2): col = lane&15, row = quad*4 + reg.
    float rs[4][4];
    float cs[4];
#pragma unroll
    for (int mi = 0; mi < 4; ++mi)
#pragma unroll
        for (int r = 0; r < 4; ++r) rs[mi][r] = 0.0f;
#pragma unroll
    for (int ni = 0; ni < 4; ++ni) cs[ni] = 0.0f;

#pragma unroll
    for (int mi = 0; mi < 4; ++mi)
#pragma unroll
        for (int ni = 0; ni < 4; ++ni)
#pragma unroll
            for (int r = 0; r < 4; ++r) {
                float e = __expf(acc[mi][ni][r] * INV_T);
                rs[mi][r] += e;
                cs[ni] += e;
            }

    // row sums: reduce over lane bits 0..3 (the 16 columns)
#pragma unroll
    for (int mi = 0; mi < 4; ++mi) {
#pragma unroll
        for (int r = 0; r < 4; ++r) {
            float v = rs[mi][r];
            v += __shfl_xor(v, 1, 64);
            v += __shfl_xor(v, 2, 64);
            v += __shfl_xor(v, 4, 64);
            v += __shfl_xor(v, 8, 64);
            if (lr == 0) {
                int row = row_base + wr * 64 + mi * 16 + quad * 4 + r;
                atomicAdd(&row_sumexp[row], v);
            }
        }
    }

    // col sums: reduce over lane bits 4..5
    if (!diag) {
#pragma unroll
        for (int ni = 0; ni < 4; ++ni) {
            float v = cs[ni];
            v += __shfl_xor(v, 16, 64);
            v += __shfl_xor(v, 32, 64);
            if (quad == 0) {
                int col = col_base + wc * 64 + ni * 16 + lr;
                atomicAdd(&row_sumexp[col], v);
            }
        }
    }
}

// ---------------- Kernel 3: tiny finisher ----------------
// grid 16 x 256: one thread per pair index.
__global__ void k_final(const float* __restrict__ row_sumexp,
                        const float* __restrict__ e_diag,
                        const float* __restrict__ pos,
                        float* __restrict__ out) {
    const int i    = blockIdx.x * 256 + threadIdx.x;   // 0..4095
    const int w    = threadIdx.x >> 6;
    const int lane = threadIdx.x & 63;

    float t = logf(row_sumexp[i] - e_diag[i])
            + logf(row_sumexp[i + NPAIR] - e_diag[i + NPAIR])
            - 2.0f * pos[i];
#pragma unroll
    for (int m = 1; m < 64; m <<= 1) t += __shfl_xor(t, m, 64);

    __shared__ float ps[4];
    if (lane == 0) ps[w] = t;
    __syncthreads();
    if (threadIdx.x == 0) {
        float s = (ps[0] + ps[1] + ps[2] + ps[3]) * (1.0f / (float)TWO_N);
        atomicAdd(out, s);
    }
}

extern "C" void kernel_launch(void* const* d_in, const int* in_sizes, int n_in,
                              void* d_out, int out_size, void* d_ws, size_t ws_size,
                              hipStream_t stream) {
    const float* z1 = (const float*)d_in[0];
    const float* z2 = (const float*)d_in[1];
    float* out = (float*)d_out;

    char* ws = (char*)d_ws;
    __hip_bfloat16* zn  = (__hip_bfloat16*)ws;                       // 4 MB
    float* row_sumexp   = (float*)(ws + (size_t)TWO_N * DDIM * 2);   // 32 KB
    float* e_diag       = row_sumexp + TWO_N;                        // 32 KB
    float* pos          = e_diag + TWO_N;                            // 16 KB

    k_normalize<<<NPAIR / 4, 256, 0, stream>>>(z1, z2, zn, e_diag, pos,
                                               row_sumexp, out);
    k_gemm_sumexp<<<NBLK, 256, 0, stream>>>(zn, row_sumexp);
    k_final<<<NPAIR / 256, 256, 0, stream>>>(row_sumexp, e_diag, pos, out);
}